// Round 6
// baseline (63.259 us; speedup 1.0000x reference)
//
#include <hip/hip_runtime.h>

#define N_TOKS 1024
#define N_ATOMS 4096
#define CS 384
#define CZ 128
#define CATOM 128
#define CPAIR 16
#define NQ 32
#define NK 128
#define NBLK 128           // N_ATOMS / NQ
#define KOFF (-48)         // NQ/2 - NK/2
#define KSEG 16
#define NSEG (NK / KSEG)   // 8
#define NB_B (NBLK * NSEG) // 1024 B-role blocks (x < NB_B)
#define NB_A 256           // A-role blocks
#define MAXP 256           // ztile chunk capacity (pairs)
#define LN_EPS 1e-5f

union alignas(16) SMem {
    struct {
        float ztile[MAXP * CPAIR];        // 16 KB compact pair tile
        int ends[N_TOKS];                 // 4 KB
        int tokq[NQ]; int tokk[KSEG];
        int qmap[NQ]; int kmap[KSEG];
        int uqtok[NQ]; int uktok[KSEG];
        float kvalid[KSEG];
        int uqk[2];
        int wsum[4];
    } b;
    struct {
        float xh[CS][4];                  // 6 KB
        float sacc[8][4][CATOM];          // 16 KB
        float s_l[4][CATOM];              // 2 KB
        int ends[N_TOKS];                 // 4 KB
        int wsum[4];
    } a;
};

// shuffle-based scan of na[0..1023] -> inclusive ends[] in LDS (2 barriers)
__device__ __forceinline__ void scan_ends(const int* __restrict__ na, int* ends, int* wsum, int t) {
    int4 v = ((const int4*)na)[t];
    int e0 = v.x, e1 = e0 + v.y, e2 = e1 + v.z, e3 = e2 + v.w;
    int s = e3;
    int lane = t & 63, w = t >> 6;
    #pragma unroll
    for (int off = 1; off < 64; off <<= 1) {
        int u = __shfl_up(s, off);
        if (lane >= off) s += u;
    }
    if (lane == 63) wsum[w] = s;
    __syncthreads();
    int wbase = 0;
    #pragma unroll
    for (int i = 0; i < 4; i++) wbase += (i < w) ? wsum[i] : 0;
    int base = wbase + s - e3;
    ends[4 * t + 0] = base + e0;
    ends[4 * t + 1] = base + e1;
    ends[4 * t + 2] = base + e2;
    ends[4 * t + 3] = base + e3;
    __syncthreads();
}

__device__ __forceinline__ int bsearch_tok(const int* ends, int a) {
    int lo = 0, hi = N_TOKS - 1;
    while (lo < hi) { int mid = (lo + hi) >> 1; if (ends[mid] > a) hi = mid; else lo = mid + 1; }
    return lo;
}

__global__ __launch_bounds__(256) void k_all(
        const int* __restrict__ na, const float* __restrict__ si,
        const float* __restrict__ lnw, const float* __restrict__ Ws,
        const float* __restrict__ bs, const float* __restrict__ mask,
        const float* __restrict__ cl, const float* __restrict__ rl,
        const float* __restrict__ Wr, const float* __restrict__ br,
        const float* __restrict__ zij, const float* __restrict__ lnzw,
        const float* __restrict__ Wz, const float* __restrict__ bz,
        const float* __restrict__ plm,
        float* __restrict__ cl_out, float* __restrict__ ql, float* __restrict__ plm_out) {
    __shared__ SMem sm;
    int t = threadIdx.x;
    int x = blockIdx.x;

    if (x >= NB_B) {
        // ================= A role: s = LN(si)@Ws+bs ; cl_out ; ql =================
        int b = x - NB_B, Tlo = b * 4;
        scan_ends(na, sm.a.ends, sm.a.wsum, t);
        {
            int tl = t >> 6, l = t & 63;
            const float4* row4 = (const float4*)(si + (size_t)(Tlo + tl) * CS);
            float4 v0 = row4[l];
            float4 v1 = make_float4(0.f, 0.f, 0.f, 0.f);
            if (l < 32) v1 = row4[64 + l];
            float sum = v0.x + v0.y + v0.z + v0.w + v1.x + v1.y + v1.z + v1.w;
            float sq = v0.x*v0.x + v0.y*v0.y + v0.z*v0.z + v0.w*v0.w
                     + v1.x*v1.x + v1.y*v1.y + v1.z*v1.z + v1.w*v1.w;
            #pragma unroll
            for (int m = 32; m >= 1; m >>= 1) { sum += __shfl_xor(sum, m); sq += __shfl_xor(sq, m); }
            float mu = sum * (1.f / CS);
            float rstd = rsqrtf(sq * (1.f / CS) - mu * mu + LN_EPS);
            float4 g0 = ((const float4*)lnw)[l];
            sm.a.xh[4*l+0][tl] = (v0.x - mu) * rstd * g0.x;
            sm.a.xh[4*l+1][tl] = (v0.y - mu) * rstd * g0.y;
            sm.a.xh[4*l+2][tl] = (v0.z - mu) * rstd * g0.z;
            sm.a.xh[4*l+3][tl] = (v0.w - mu) * rstd * g0.w;
            if (l < 32) {
                float4 g1 = ((const float4*)lnw)[64 + l];
                sm.a.xh[256+4*l+0][tl] = (v1.x - mu) * rstd * g1.x;
                sm.a.xh[256+4*l+1][tl] = (v1.y - mu) * rstd * g1.y;
                sm.a.xh[256+4*l+2][tl] = (v1.z - mu) * rstd * g1.z;
                sm.a.xh[256+4*l+3][tl] = (v1.w - mu) * rstd * g1.w;
            }
        }
        __syncthreads();
        {
            int d4 = t & 31, cc = t >> 5;
            float4 a0 = make_float4(0,0,0,0), a1 = a0, a2 = a0, a3 = a0;
            const float4* Ws4 = (const float4*)Ws;
            int c0 = 48 * cc;
            #pragma unroll 4
            for (int c = c0; c < c0 + 48; c++) {
                float4 w = Ws4[(size_t)c * 32 + d4];
                float4 xv = *(const float4*)&sm.a.xh[c][0];
                a0.x += xv.x * w.x; a0.y += xv.x * w.y; a0.z += xv.x * w.z; a0.w += xv.x * w.w;
                a1.x += xv.y * w.x; a1.y += xv.y * w.y; a1.z += xv.y * w.z; a1.w += xv.y * w.w;
                a2.x += xv.z * w.x; a2.y += xv.z * w.y; a2.z += xv.z * w.z; a2.w += xv.z * w.w;
                a3.x += xv.w * w.x; a3.y += xv.w * w.y; a3.z += xv.w * w.z; a3.w += xv.w * w.w;
            }
            *(float4*)&sm.a.sacc[cc][0][d4 * 4] = a0;
            *(float4*)&sm.a.sacc[cc][1][d4 * 4] = a1;
            *(float4*)&sm.a.sacc[cc][2][d4 * 4] = a2;
            *(float4*)&sm.a.sacc[cc][3][d4 * 4] = a3;
        }
        __syncthreads();
        if (t < 128) {
            int tk = t >> 5, d = t & 31;
            float4 a = make_float4(0,0,0,0);
            #pragma unroll
            for (int cc = 0; cc < 8; cc++) {
                float4 p = *(const float4*)&sm.a.sacc[cc][tk][d * 4];
                a.x += p.x; a.y += p.y; a.z += p.z; a.w += p.w;
            }
            float4 bb = ((const float4*)bs)[d];
            float m = mask[Tlo + tk];
            a.x = (a.x + bb.x) * m; a.y = (a.y + bb.y) * m;
            a.z = (a.z + bb.z) * m; a.w = (a.w + bb.w) * m;
            *(float4*)&sm.a.s_l[tk][d * 4] = a;
        }
        __syncthreads();
        int elo = (Tlo == 0) ? 0 : sm.a.ends[Tlo - 1];
        int e_0 = sm.a.ends[Tlo], e_1 = sm.a.ends[Tlo + 1], e_2 = sm.a.ends[Tlo + 2];
        int ehi = (b == NB_A - 1) ? N_ATOMS : sm.a.ends[Tlo + 3];
        elo = min(max(elo, 0), N_ATOMS);
        ehi = min(max(ehi, 0), N_ATOMS);
        if (ehi < elo) ehi = elo;
        int items = (ehi - elo) * 32;
        for (int i = t; i < items; i += 256) {
            int a = elo + (i >> 5), d = i & 31;
            int tk = (a >= e_0) + (a >= e_1) + (a >= e_2);
            float4 c4 = ((const float4*)cl)[(size_t)a * 32 + d];
            float4 sv = *(const float4*)&sm.a.s_l[tk][d * 4];
            float4 co;
            co.x = c4.x + sv.x; co.y = c4.y + sv.y; co.z = c4.z + sv.z; co.w = c4.w + sv.w;
            float px = rl[a * 3 + 0], py = rl[a * 3 + 1], pz = rl[a * 3 + 2];
            float4 w0 = ((const float4*)Wr)[d];
            float4 w1 = ((const float4*)Wr)[32 + d];
            float4 w2 = ((const float4*)Wr)[64 + d];
            float4 bb = ((const float4*)br)[d];
            float4 q;
            q.x = co.x + px * w0.x + py * w1.x + pz * w2.x + bb.x;
            q.y = co.y + px * w0.y + py * w1.y + pz * w2.y + bb.y;
            q.z = co.z + px * w0.z + py * w1.z + pz * w2.z + bb.z;
            q.w = co.w + px * w0.w + py * w1.w + pz * w2.w + bb.w;
            ((float4*)cl_out)[(size_t)a * 32 + d] = co;
            ((float4*)ql)[(size_t)a * 32 + d] = q;
        }
        return;
    }

    // ================= B role: z at gathered pairs + plm stream =================
    int blk = x >> 3, kseg = x & 7;

    // prefetch plm into registers first (T14): latency hides under scan+dedup+phase-1
    const float4* plm4 = (const float4*)plm;
    float4 pv[8];
    #pragma unroll
    for (int i = 0; i < 8; i++) {
        int f = t + i * 256;           // 0..2047
        int d4 = f & 3;
        int kk = (f >> 2) & 15;
        int q  = f >> 6;
        size_t g = ((size_t)(blk * NQ + q) * NK + (size_t)kseg * KSEG + kk) * (CPAIR / 4) + d4;
        pv[i] = plm4[g];
    }

    scan_ends(na, sm.b.ends, sm.b.wsum, t);

    if (t < NQ) {
        sm.b.tokq[t] = bsearch_tok(sm.b.ends, blk * NQ + t);
    } else if (t >= 64 && t < 64 + KSEG) {
        int kk = t - 64;
        int kg = blk * NQ + KOFF + kseg * KSEG + kk;
        sm.b.kvalid[kk] = (kg >= 0 && kg < N_ATOMS) ? 1.0f : 0.0f;
        sm.b.tokk[kk] = bsearch_tok(sm.b.ends, min(max(kg, 0), N_ATOMS - 1));
    }
    __syncthreads();

    // wave-parallel dedup via ballot (wave 0: q side, wave 1: k side)
    if (t < NQ) {
        int tq = sm.b.tokq[t];
        bool head = (t == 0) || (tq != sm.b.tokq[t - 1]);
        unsigned long long m = __ballot(head);
        int rank = (int)__popcll(m & ((2ull << t) - 1)) - 1;
        sm.b.qmap[t] = rank;
        if (head) sm.b.uqtok[rank] = tq;
        if (t == 0) sm.b.uqk[0] = (int)__popcll(m);
    } else if (t >= 64 && t < 64 + KSEG) {
        int lane = t - 64;
        int tk = sm.b.tokk[lane];
        bool head = (lane == 0) || (tk != sm.b.tokk[lane - 1]);
        unsigned long long m = __ballot(head);
        int rank = (int)__popcll(m & ((2ull << lane) - 1)) - 1;
        sm.b.kmap[lane] = rank;
        if (head) sm.b.uktok[rank] = tk;
        if (lane == 0) sm.b.uqk[1] = (int)__popcll(m);
    }
    __syncthreads();
    int uq = sm.b.uqk[0], uk = sm.b.uqk[1];
    int npairs = uq * uk;      // typical ~40, worst 512

    int sl = t & 7;            // 8 lanes per pair; lane covers channels [sl*16, sl*16+16)
    const float4* bz4 = (const float4*)bz;
    float4 bz0 = bz4[0], bz1 = bz4[1], bz2 = bz4[2], bz3 = bz4[3];

    for (int c0 = 0; c0 < npairs; c0 += MAXP) {
        int cend = min(npairs, c0 + MAXP);
        // ---- phase 1: compute z for pairs [c0, cend), 8 lanes/pair, single zij pass ----
        for (int p = c0 + (t >> 3); p < cend; p += 32) {
            int qi = p / uk, ki = p - qi * uk;
            const float4* rp = (const float4*)(zij + ((size_t)sm.b.uqtok[qi] * N_TOKS + sm.b.uktok[ki]) * CZ + sl * 16);
            float4 v0 = rp[0], v1 = rp[1], v2 = rp[2], v3 = rp[3];
            float sum = v0.x+v0.y+v0.z+v0.w + v1.x+v1.y+v1.z+v1.w
                      + v2.x+v2.y+v2.z+v2.w + v3.x+v3.y+v3.z+v3.w;
            float sq = v0.x*v0.x+v0.y*v0.y+v0.z*v0.z+v0.w*v0.w
                     + v1.x*v1.x+v1.y*v1.y+v1.z*v1.z+v1.w*v1.w
                     + v2.x*v2.x+v2.y*v2.y+v2.z*v2.z+v2.w*v2.w
                     + v3.x*v3.x+v3.y*v3.y+v3.z*v3.z+v3.w*v3.w;
            sum += __shfl_xor(sum, 1); sq += __shfl_xor(sq, 1);
            sum += __shfl_xor(sum, 2); sq += __shfl_xor(sq, 2);
            sum += __shfl_xor(sum, 4); sq += __shfl_xor(sq, 4);
            float mu = sum * (1.f / CZ);
            float rstd = rsqrtf(sq * (1.f / CZ) - mu * mu + LN_EPS);
            const float4* l4 = (const float4*)(lnzw + sl * 16);
            float4 g0 = l4[0], g1 = l4[1], g2 = l4[2], g3 = l4[3];
            v0.x = (v0.x-mu)*rstd*g0.x; v0.y = (v0.y-mu)*rstd*g0.y; v0.z = (v0.z-mu)*rstd*g0.z; v0.w = (v0.w-mu)*rstd*g0.w;
            v1.x = (v1.x-mu)*rstd*g1.x; v1.y = (v1.y-mu)*rstd*g1.y; v1.z = (v1.z-mu)*rstd*g1.z; v1.w = (v1.w-mu)*rstd*g1.w;
            v2.x = (v2.x-mu)*rstd*g2.x; v2.y = (v2.y-mu)*rstd*g2.y; v2.z = (v2.z-mu)*rstd*g2.z; v2.w = (v2.w-mu)*rstd*g2.w;
            v3.x = (v3.x-mu)*rstd*g3.x; v3.y = (v3.y-mu)*rstd*g3.y; v3.z = (v3.z-mu)*rstd*g3.z; v3.w = (v3.w-mu)*rstd*g3.w;
            float acc[16];
            #pragma unroll
            for (int d = 0; d < 16; d++) acc[d] = 0.f;
            const float4* Wp = (const float4*)(Wz + sl * 16 * CPAIR);
            #define CH(J, XV) { \
                float4 w0 = Wp[(J)*4+0], w1 = Wp[(J)*4+1], w2 = Wp[(J)*4+2], w3 = Wp[(J)*4+3]; \
                acc[ 0] += (XV)*w0.x; acc[ 1] += (XV)*w0.y; acc[ 2] += (XV)*w0.z; acc[ 3] += (XV)*w0.w; \
                acc[ 4] += (XV)*w1.x; acc[ 5] += (XV)*w1.y; acc[ 6] += (XV)*w1.z; acc[ 7] += (XV)*w1.w; \
                acc[ 8] += (XV)*w2.x; acc[ 9] += (XV)*w2.y; acc[10] += (XV)*w2.z; acc[11] += (XV)*w2.w; \
                acc[12] += (XV)*w3.x; acc[13] += (XV)*w3.y; acc[14] += (XV)*w3.z; acc[15] += (XV)*w3.w; }
            CH(0, v0.x) CH(1, v0.y) CH(2, v0.z) CH(3, v0.w)
            CH(4, v1.x) CH(5, v1.y) CH(6, v1.z) CH(7, v1.w)
            CH(8, v2.x) CH(9, v2.y) CH(10, v2.z) CH(11, v2.w)
            CH(12, v3.x) CH(13, v3.y) CH(14, v3.z) CH(15, v3.w)
            #undef CH
            #pragma unroll
            for (int d = 0; d < 16; d++) {
                acc[d] += __shfl_xor(acc[d], 1);
                acc[d] += __shfl_xor(acc[d], 2);
                acc[d] += __shfl_xor(acc[d], 4);
            }
            if (sl == 0) {
                float* zt = &sm.b.ztile[(p - c0) * CPAIR];
                *(float4*)&zt[ 0] = make_float4(acc[ 0]+bz0.x, acc[ 1]+bz0.y, acc[ 2]+bz0.z, acc[ 3]+bz0.w);
                *(float4*)&zt[ 4] = make_float4(acc[ 4]+bz1.x, acc[ 5]+bz1.y, acc[ 6]+bz1.z, acc[ 7]+bz1.w);
                *(float4*)&zt[ 8] = make_float4(acc[ 8]+bz2.x, acc[ 9]+bz2.y, acc[10]+bz2.z, acc[11]+bz2.w);
                *(float4*)&zt[12] = make_float4(acc[12]+bz3.x, acc[13]+bz3.y, acc[14]+bz3.z, acc[15]+bz3.w);
            }
        }
        __syncthreads();
        // ---- phase 2 partial: add this chunk's z into prefetched plm ----
        #pragma unroll
        for (int i = 0; i < 8; i++) {
            int f = t + i * 256;
            int d4 = f & 3;
            int kk = (f >> 2) & 15;
            int q  = f >> 6;
            int pidx = sm.b.qmap[q] * uk + sm.b.kmap[kk];
            if (pidx >= c0 && pidx < cend) {
                float vd = sm.b.kvalid[kk];
                const float4 z = *(const float4*)&sm.b.ztile[(pidx - c0) * CPAIR + d4 * 4];
                pv[i].x += vd * z.x; pv[i].y += vd * z.y;
                pv[i].z += vd * z.z; pv[i].w += vd * z.w;
            }
        }
        __syncthreads();
    }

    // ---- store ----
    float4* out4 = (float4*)plm_out;
    #pragma unroll
    for (int i = 0; i < 8; i++) {
        int f = t + i * 256;
        int d4 = f & 3;
        int kk = (f >> 2) & 15;
        int q  = f >> 6;
        size_t g = ((size_t)(blk * NQ + q) * NK + (size_t)kseg * KSEG + kk) * (CPAIR / 4) + d4;
        out4[g] = pv[i];
    }
}

extern "C" void kernel_launch(void* const* d_in, const int* in_sizes, int n_in,
                              void* d_out, int out_size, void* d_ws, size_t ws_size,
                              hipStream_t stream) {
    (void)in_sizes; (void)n_in; (void)out_size; (void)d_ws; (void)ws_size;
    const float* token_mask = (const float*)d_in[0];
    const int*   num_atoms  = (const int*)d_in[1];
    const float* cl   = (const float*)d_in[2];
    const float* plm  = (const float*)d_in[3];
    const float* si   = (const float*)d_in[4];
    const float* zij  = (const float*)d_in[5];
    const float* rl   = (const float*)d_in[6];
    const float* ln_s_w = (const float*)d_in[7];
    const float* W_s  = (const float*)d_in[8];
    const float* b_s  = (const float*)d_in[9];
    const float* ln_z_w = (const float*)d_in[10];
    const float* W_z  = (const float*)d_in[11];
    const float* b_z  = (const float*)d_in[12];
    const float* W_r  = (const float*)d_in[13];
    const float* b_r  = (const float*)d_in[14];

    float* out_cl  = (float*)d_out;
    float* out_plm = out_cl + (size_t)N_ATOMS * CATOM;
    float* out_ql  = out_plm + (size_t)NBLK * NQ * NK * CPAIR;

    k_all<<<NB_B + NB_A, 256, 0, stream>>>(num_atoms, si, ln_s_w, W_s, b_s, token_mask,
                                           cl, rl, W_r, b_r,
                                           zij, ln_z_w, W_z, b_z, plm,
                                           out_cl, out_ql, out_plm);
}

// Round 7
// 35.533 us; speedup vs baseline: 1.7803x; 1.7803x over previous
//
#include <hip/hip_runtime.h>

#define N_TOKS 1024
#define N_ATOMS 4096
#define CS 384
#define CZ 128
#define CATOM 128
#define CPAIR 16
#define NQ 32
#define NK 128
#define NBLK 128           // N_ATOMS / NQ
#define KOFF (-48)         // NQ/2 - NK/2
#define KSEG 32
#define NSEG (NK / KSEG)   // 4
#define NTILE (NBLK * NSEG) // 512 z-tiles
#define NB_A 256
#define MAXP 1024          // worst-case pairs per tile (32x32)
#define MAPSTRIDE 68       // ints per tile: [0]=uk, [1..32]=qmap, [33..64]=kmap, [65]=validmask
#define LN_EPS 1e-5f

union alignas(16) SMem {
    struct {
        int ends[N_TOKS];
        int tokq[NQ]; int tokk[KSEG];
        int qmap[NQ]; int kmap[KSEG];
        int uqtok[NQ]; int uktok[KSEG];
        int uqk[2];
        int wsum[4];
        int vmask;
    } b;
    struct {
        float xh[CS][4];
        float sacc[8][4][CATOM];
        float s_l[4][CATOM];
        int ends[N_TOKS];
        int wsum[4];
    } a;
};

// shuffle-based scan of na[0..1023] -> inclusive ends[] in LDS (2 barriers)
__device__ __forceinline__ void scan_ends(const int* __restrict__ na, int* ends, int* wsum, int t) {
    int4 v = ((const int4*)na)[t];
    int e0 = v.x, e1 = e0 + v.y, e2 = e1 + v.z, e3 = e2 + v.w;
    int s = e3;
    int lane = t & 63, w = t >> 6;
    #pragma unroll
    for (int off = 1; off < 64; off <<= 1) {
        int u = __shfl_up(s, off);
        if (lane >= off) s += u;
    }
    if (lane == 63) wsum[w] = s;
    __syncthreads();
    int wbase = 0;
    #pragma unroll
    for (int i = 0; i < 4; i++) wbase += (i < w) ? wsum[i] : 0;
    int base = wbase + s - e3;
    ends[4 * t + 0] = base + e0;
    ends[4 * t + 1] = base + e1;
    ends[4 * t + 2] = base + e2;
    ends[4 * t + 3] = base + e3;
    __syncthreads();
}

__device__ __forceinline__ int bsearch_tok(const int* ends, int a) {
    int lo = 0, hi = N_TOKS - 1;
    while (lo < hi) { int mid = (lo + hi) >> 1; if (ends[mid] > a) hi = mid; else lo = mid + 1; }
    return lo;
}

// ============ k_pre: blocks 0..511 = B z-compute -> ws ; blocks 512..767 = A role ============
__global__ __launch_bounds__(256) void k_pre(
        const int* __restrict__ na, const float* __restrict__ si,
        const float* __restrict__ lnw, const float* __restrict__ Ws,
        const float* __restrict__ bs, const float* __restrict__ mask,
        const float* __restrict__ cl, const float* __restrict__ rl,
        const float* __restrict__ Wr, const float* __restrict__ br,
        const float* __restrict__ zij, const float* __restrict__ lnzw,
        const float* __restrict__ Wz, const float* __restrict__ bz,
        float* __restrict__ z_ws, int* __restrict__ maps_ws,
        float* __restrict__ cl_out, float* __restrict__ ql) {
    __shared__ SMem sm;
    int t = threadIdx.x;
    int x = blockIdx.x;

    if (x >= NTILE) {
        // ================= A role (R4-proven, verbatim) =================
        int b = x - NTILE, Tlo = b * 4;
        scan_ends(na, sm.a.ends, sm.a.wsum, t);
        {
            int tl = t >> 6, l = t & 63;
            const float4* row4 = (const float4*)(si + (size_t)(Tlo + tl) * CS);
            float4 v0 = row4[l];
            float4 v1 = make_float4(0.f, 0.f, 0.f, 0.f);
            if (l < 32) v1 = row4[64 + l];
            float sum = v0.x + v0.y + v0.z + v0.w + v1.x + v1.y + v1.z + v1.w;
            float sq = v0.x*v0.x + v0.y*v0.y + v0.z*v0.z + v0.w*v0.w
                     + v1.x*v1.x + v1.y*v1.y + v1.z*v1.z + v1.w*v1.w;
            #pragma unroll
            for (int m = 32; m >= 1; m >>= 1) { sum += __shfl_xor(sum, m); sq += __shfl_xor(sq, m); }
            float mu = sum * (1.f / CS);
            float rstd = rsqrtf(sq * (1.f / CS) - mu * mu + LN_EPS);
            float4 g0 = ((const float4*)lnw)[l];
            sm.a.xh[4*l+0][tl] = (v0.x - mu) * rstd * g0.x;
            sm.a.xh[4*l+1][tl] = (v0.y - mu) * rstd * g0.y;
            sm.a.xh[4*l+2][tl] = (v0.z - mu) * rstd * g0.z;
            sm.a.xh[4*l+3][tl] = (v0.w - mu) * rstd * g0.w;
            if (l < 32) {
                float4 g1 = ((const float4*)lnw)[64 + l];
                sm.a.xh[256+4*l+0][tl] = (v1.x - mu) * rstd * g1.x;
                sm.a.xh[256+4*l+1][tl] = (v1.y - mu) * rstd * g1.y;
                sm.a.xh[256+4*l+2][tl] = (v1.z - mu) * rstd * g1.z;
                sm.a.xh[256+4*l+3][tl] = (v1.w - mu) * rstd * g1.w;
            }
        }
        __syncthreads();
        {
            int d4 = t & 31, cc = t >> 5;
            float4 a0 = make_float4(0,0,0,0), a1 = a0, a2 = a0, a3 = a0;
            const float4* Ws4 = (const float4*)Ws;
            int c0 = 48 * cc;
            #pragma unroll 4
            for (int c = c0; c < c0 + 48; c++) {
                float4 w = Ws4[(size_t)c * 32 + d4];
                float4 xv = *(const float4*)&sm.a.xh[c][0];
                a0.x += xv.x * w.x; a0.y += xv.x * w.y; a0.z += xv.x * w.z; a0.w += xv.x * w.w;
                a1.x += xv.y * w.x; a1.y += xv.y * w.y; a1.z += xv.y * w.z; a1.w += xv.y * w.w;
                a2.x += xv.z * w.x; a2.y += xv.z * w.y; a2.z += xv.z * w.z; a2.w += xv.z * w.w;
                a3.x += xv.w * w.x; a3.y += xv.w * w.y; a3.z += xv.w * w.z; a3.w += xv.w * w.w;
            }
            *(float4*)&sm.a.sacc[cc][0][d4 * 4] = a0;
            *(float4*)&sm.a.sacc[cc][1][d4 * 4] = a1;
            *(float4*)&sm.a.sacc[cc][2][d4 * 4] = a2;
            *(float4*)&sm.a.sacc[cc][3][d4 * 4] = a3;
        }
        __syncthreads();
        if (t < 128) {
            int tk = t >> 5, d = t & 31;
            float4 a = make_float4(0,0,0,0);
            #pragma unroll
            for (int cc = 0; cc < 8; cc++) {
                float4 p = *(const float4*)&sm.a.sacc[cc][tk][d * 4];
                a.x += p.x; a.y += p.y; a.z += p.z; a.w += p.w;
            }
            float4 bb = ((const float4*)bs)[d];
            float m = mask[Tlo + tk];
            a.x = (a.x + bb.x) * m; a.y = (a.y + bb.y) * m;
            a.z = (a.z + bb.z) * m; a.w = (a.w + bb.w) * m;
            *(float4*)&sm.a.s_l[tk][d * 4] = a;
        }
        __syncthreads();
        int elo = (Tlo == 0) ? 0 : sm.a.ends[Tlo - 1];
        int e_0 = sm.a.ends[Tlo], e_1 = sm.a.ends[Tlo + 1], e_2 = sm.a.ends[Tlo + 2];
        int ehi = (b == NB_A - 1) ? N_ATOMS : sm.a.ends[Tlo + 3];
        elo = min(max(elo, 0), N_ATOMS);
        ehi = min(max(ehi, 0), N_ATOMS);
        if (ehi < elo) ehi = elo;
        int items = (ehi - elo) * 32;
        for (int i = t; i < items; i += 256) {
            int a = elo + (i >> 5), d = i & 31;
            int tk = (a >= e_0) + (a >= e_1) + (a >= e_2);
            float4 c4 = ((const float4*)cl)[(size_t)a * 32 + d];
            float4 sv = *(const float4*)&sm.a.s_l[tk][d * 4];
            float4 co;
            co.x = c4.x + sv.x; co.y = c4.y + sv.y; co.z = c4.z + sv.z; co.w = c4.w + sv.w;
            float px = rl[a * 3 + 0], py = rl[a * 3 + 1], pz = rl[a * 3 + 2];
            float4 w0 = ((const float4*)Wr)[d];
            float4 w1 = ((const float4*)Wr)[32 + d];
            float4 w2 = ((const float4*)Wr)[64 + d];
            float4 bb = ((const float4*)br)[d];
            float4 q;
            q.x = co.x + px * w0.x + py * w1.x + pz * w2.x + bb.x;
            q.y = co.y + px * w0.y + py * w1.y + pz * w2.y + bb.y;
            q.z = co.z + px * w0.z + py * w1.z + pz * w2.z + bb.z;
            q.w = co.w + px * w0.w + py * w1.w + pz * w2.w + bb.w;
            ((float4*)cl_out)[(size_t)a * 32 + d] = co;
            ((float4*)ql)[(size_t)a * 32 + d] = q;
        }
        return;
    }

    // ================= B role: z at unique pairs -> z_ws, maps -> maps_ws =================
    int blk = x >> 2, kseg = x & 3;
    scan_ends(na, sm.b.ends, sm.b.wsum, t);

    if (t < NQ) {
        sm.b.tokq[t] = bsearch_tok(sm.b.ends, blk * NQ + t);
    } else if (t >= 64 && t < 64 + KSEG) {
        int kk = t - 64;
        int kg = blk * NQ + KOFF + kseg * KSEG + kk;
        bool val = (kg >= 0 && kg < N_ATOMS);
        unsigned long long vm = __ballot(val);
        if (kk == 0) sm.b.vmask = (int)(vm & 0xffffffffull);
        sm.b.tokk[kk] = bsearch_tok(sm.b.ends, min(max(kg, 0), N_ATOMS - 1));
    }
    __syncthreads();

    // wave-parallel dedup via ballot (wave 0: q side, wave 1: k side)
    if (t < NQ) {
        int tq = sm.b.tokq[t];
        bool head = (t == 0) || (tq != sm.b.tokq[t - 1]);
        unsigned long long m = __ballot(head);
        int rank = (int)__popcll(m & ((2ull << t) - 1)) - 1;
        sm.b.qmap[t] = rank;
        if (head) sm.b.uqtok[rank] = tq;
        if (t == 0) sm.b.uqk[0] = (int)__popcll(m);
    } else if (t >= 64 && t < 64 + KSEG) {
        int lane = t - 64;
        int tk = sm.b.tokk[lane];
        bool head = (lane == 0) || (tk != sm.b.tokk[lane - 1]);
        unsigned long long m = __ballot(head);
        int rank = (int)__popcll(m & ((2ull << lane) - 1)) - 1;
        sm.b.kmap[lane] = rank;
        if (head) sm.b.uktok[rank] = tk;
        if (lane == 0) sm.b.uqk[1] = (int)__popcll(m);
    }
    __syncthreads();
    int uq = sm.b.uqk[0], uk = sm.b.uqk[1];
    int npairs = uq * uk;      // typical ~72, worst 1024

    // write maps
    int* mp = maps_ws + x * MAPSTRIDE;
    if (t < NQ) mp[1 + t] = sm.b.qmap[t];
    else if (t >= 64 && t < 64 + KSEG) mp[33 + (t - 64)] = sm.b.kmap[t - 64];
    else if (t == 96) mp[0] = uk;
    else if (t == 97) mp[65] = sm.b.vmask;

    // phase 1: z at unique pairs, 1 lane per pair (register-lean, R4-proven) -> z_ws
    for (int p = t; p < npairs; p += 256) {
        int qi = p / uk, ki = p - qi * uk;
        int tq = sm.b.uqtok[qi], tk = sm.b.uktok[ki];
        const float* row = zij + ((size_t)tq * N_TOKS + tk) * CZ;
        float sum = 0.f, sq = 0.f;
        for (int c4 = 0; c4 < CZ / 4; c4++) {
            float4 v = *(const float4*)(row + c4 * 4);
            sum += v.x + v.y + v.z + v.w;
            sq  += v.x * v.x + v.y * v.y + v.z * v.z + v.w * v.w;
        }
        float mu = sum * (1.f / CZ);
        float rstd = rsqrtf(sq * (1.f / CZ) - mu * mu + LN_EPS);
        float acc[CPAIR];
        #pragma unroll
        for (int d = 0; d < CPAIR; d++) acc[d] = bz[d];
        for (int c4 = 0; c4 < CZ / 4; c4++) {
            float4 v = *(const float4*)(row + c4 * 4);
            float xs4[4] = {v.x, v.y, v.z, v.w};
            #pragma unroll
            for (int j = 0; j < 4; j++) {
                int c = c4 * 4 + j;
                float xv = (xs4[j] - mu) * rstd * lnzw[c];
                const float* wrow = Wz + c * CPAIR;
                #pragma unroll
                for (int d = 0; d < CPAIR; d++) acc[d] += xv * wrow[d];
            }
        }
        float4* zt = (float4*)(z_ws + ((size_t)x * MAXP + p) * CPAIR);
        zt[0] = make_float4(acc[0], acc[1], acc[2], acc[3]);
        zt[1] = make_float4(acc[4], acc[5], acc[6], acc[7]);
        zt[2] = make_float4(acc[8], acc[9], acc[10], acc[11]);
        zt[3] = make_float4(acc[12], acc[13], acc[14], acc[15]);
    }
}

// ============ k_stream: pure BW phase, 2048 blocks, quarter-tile each ============
__global__ __launch_bounds__(256) void k_stream(
        const float* __restrict__ z_ws, const int* __restrict__ maps_ws,
        const float* __restrict__ plm, float* __restrict__ plm_out) {
    __shared__ int qmap_l[8];
    __shared__ int kmap_l[32];
    __shared__ int s_uk, s_vm;
    int t = threadIdx.x;
    int b = blockIdx.x;            // 0..2047
    int tau = b >> 2, qq = b & 3;  // tile, q-quarter
    int blk = tau >> 2, kseg = tau & 3;

    const int* mp = maps_ws + tau * MAPSTRIDE;
    if (t < 32) kmap_l[t] = mp[33 + t];
    else if (t < 40) qmap_l[t - 32] = mp[1 + qq * 8 + (t - 32)];
    else if (t == 40) s_uk = mp[0];
    else if (t == 41) s_vm = mp[65];
    __syncthreads();
    int uk = s_uk, vm = s_vm;

    const float4* plm4 = (const float4*)plm;
    const float4* z4 = (const float4*)z_ws;
    float4* out4 = (float4*)plm_out;
    #pragma unroll
    for (int i = 0; i < 4; i++) {
        int f = t + i * 256;           // 0..1023 : 8q x 32k x 4d4
        int d4 = f & 3;
        int kk = (f >> 2) & 31;
        int q  = f >> 7;
        int grow = blk * NQ + qq * 8 + q;
        size_t g = ((size_t)grow * NK + kseg * KSEG + kk) * 4 + d4;
        float4 v = plm4[g];
        int pidx = qmap_l[q] * uk + kmap_l[kk];
        float4 z = z4[((size_t)tau * MAXP + pidx) * 4 + d4];
        float vd = ((vm >> kk) & 1) ? 1.0f : 0.0f;
        v.x += vd * z.x; v.y += vd * z.y; v.z += vd * z.z; v.w += vd * z.w;
        out4[g] = v;
    }
}

extern "C" void kernel_launch(void* const* d_in, const int* in_sizes, int n_in,
                              void* d_out, int out_size, void* d_ws, size_t ws_size,
                              hipStream_t stream) {
    (void)in_sizes; (void)n_in; (void)out_size; (void)ws_size;
    const float* token_mask = (const float*)d_in[0];
    const int*   num_atoms  = (const int*)d_in[1];
    const float* cl   = (const float*)d_in[2];
    const float* plm  = (const float*)d_in[3];
    const float* si   = (const float*)d_in[4];
    const float* zij  = (const float*)d_in[5];
    const float* rl   = (const float*)d_in[6];
    const float* ln_s_w = (const float*)d_in[7];
    const float* W_s  = (const float*)d_in[8];
    const float* b_s  = (const float*)d_in[9];
    const float* ln_z_w = (const float*)d_in[10];
    const float* W_z  = (const float*)d_in[11];
    const float* b_z  = (const float*)d_in[12];
    const float* W_r  = (const float*)d_in[13];
    const float* b_r  = (const float*)d_in[14];

    float* out_cl  = (float*)d_out;
    float* out_plm = out_cl + (size_t)N_ATOMS * CATOM;
    float* out_ql  = out_plm + (size_t)NBLK * NQ * NK * CPAIR;

    float* z_ws    = (float*)d_ws;                                   // 512*1024*16 f = 32 MB
    int*   maps_ws = (int*)((char*)d_ws + (size_t)NTILE * MAXP * CPAIR * 4);

    k_pre<<<NTILE + NB_A, 256, 0, stream>>>(num_atoms, si, ln_s_w, W_s, b_s, token_mask,
                                            cl, rl, W_r, b_r,
                                            zij, ln_z_w, W_z, b_z,
                                            z_ws, maps_ws, out_cl, out_ql);
    k_stream<<<NTILE * 4, 256, 0, stream>>>(z_ws, maps_ws, plm, out_plm);
}